// Round 1
// baseline (389.457 us; speedup 1.0000x reference)
//
#include <hip/hip_runtime.h>

// Problem constants
#define R_ 8
#define K_ 32
#define B_ 1024
#define D_ 256
#define L_ 16
#define BCHUNK 128   // b-rows per block in K1

// ---------------------------------------------------------------------------
// K1: fused x_ = z @ Us^T  (per r,k)  +  loss[b,r,k] = 0.5*sum_D (x - x_)^2
// grid: R_*K_ * (B_/BCHUNK) blocks, 256 threads (4 waves).
// Each lane owns 4 consecutive D columns -> float4 coalesced x_ store.
// Each wave processes 32 b-rows; z row loads are wave-uniform (scalarizable).
// ---------------------------------------------------------------------------
__global__ __launch_bounds__(256) void k1_gemm_loss(
    const float* __restrict__ x, const float* __restrict__ z,
    const float* __restrict__ Us, float* __restrict__ x_out,
    float* __restrict__ loss_ws)
{
    const int blk   = blockIdx.x;
    const int rk    = blk >> 3;        // / (B_/BCHUNK) == 8
    const int chunk = blk & 7;
    const int r = rk >> 5;             // / K_
    const int k = rk & 31;             // % K_
    const int lane = threadIdx.x & 63;
    const int wave = threadIdx.x >> 6;

    const float* Us_rk = Us + (size_t)rk * (D_ * L_);
    const float* z_rk  = z  + (size_t)rk * (B_ * L_);
    float*       xo_rk = x_out + (size_t)rk * (B_ * D_);

    // Us rows for this lane's 4 D columns -> registers (64 VGPRs), amortized
    // over 32 rows of output per wave. Reads hit L1/L2 (Us is 4 MB total).
    const int d0 = lane << 2;
    float u[4][16];
#pragma unroll
    for (int q = 0; q < 4; ++q) {
        const float4* urow = (const float4*)(Us_rk + (d0 + q) * L_);
#pragma unroll
        for (int j4 = 0; j4 < 4; ++j4) {
            float4 t = urow[j4];
            u[q][j4 * 4 + 0] = t.x; u[q][j4 * 4 + 1] = t.y;
            u[q][j4 * 4 + 2] = t.z; u[q][j4 * 4 + 3] = t.w;
        }
    }

    const int b0 = chunk * BCHUNK + wave * (BCHUNK / 4);
    for (int i = 0; i < BCHUNK / 4; ++i) {
        const int b = b0 + i;
        // z[b][0..15] — wave-uniform address
        const float4* zr = (const float4*)(z_rk + b * L_);
        float zz[16];
#pragma unroll
        for (int j4 = 0; j4 < 4; ++j4) {
            float4 t = zr[j4];
            zz[j4 * 4 + 0] = t.x; zz[j4 * 4 + 1] = t.y;
            zz[j4 * 4 + 2] = t.z; zz[j4 * 4 + 3] = t.w;
        }
        // x[b][d0..d0+3] — coalesced float4 (L2-resident, x is 1 MB)
        float4 xv = ((const float4*)(x + b * D_))[lane];

        float res[4];
#pragma unroll
        for (int q = 0; q < 4; ++q) {
            float acc = 0.f;
#pragma unroll
            for (int j = 0; j < 16; ++j) acc += zz[j] * u[q][j];
            res[q] = acc;
        }
        // coalesced 1 KB/wave store of x_
        float4 o = make_float4(res[0], res[1], res[2], res[3]);
        ((float4*)(xo_rk + (size_t)b * D_))[lane] = o;

        // fused loss: per-lane partial, then 64-lane tree reduce
        float dx0 = xv.x - res[0], dx1 = xv.y - res[1];
        float dx2 = xv.z - res[2], dx3 = xv.w - res[3];
        float sq = dx0 * dx0 + dx1 * dx1 + dx2 * dx2 + dx3 * dx3;
#pragma unroll
        for (int s = 32; s >= 1; s >>= 1) sq += __shfl_xor(sq, s, 64);
        if (lane == 0)
            loss_ws[((size_t)b * R_ + r) * K_ + k] = 0.5f * sq;
    }
}

// ---------------------------------------------------------------------------
// K2: per (b,r) pair: top-2 min over K=32, argmin (lowest index on ties,
// matching jax.lax.top_k), one-hot c (coalesced), per-pair stats to ws.
// 32 lanes per pair, 2 pairs per wave. No ws zero-init needed: every ws
// element consumed later is written here or in K1.
// ---------------------------------------------------------------------------
__global__ __launch_bounds__(256) void k2_top2(
    const float* __restrict__ loss_ws, float* __restrict__ c_out,
    float* __restrict__ top1_ws, float* __restrict__ delta_ws,
    int* __restrict__ argmin_ws)
{
    const int tid  = blockIdx.x * 256 + threadIdx.x;
    const int pair = tid >> 5;     // 0 .. B_*R_-1 == 8191
    const int kk   = tid & 31;

    const float v = loss_ws[pair * 32 + kk];

    // min + argmin; xor masks <=16 keep the two 32-lane halves independent
    float mv = v; int mi = kk;
#pragma unroll
    for (int s = 16; s >= 1; s >>= 1) {
        float ov = __shfl_xor(mv, s, 64);
        int   oi = __shfl_xor(mi, s, 64);
        if (ov < mv || (ov == mv && oi < mi)) { mv = ov; mi = oi; }
    }
    // second-smallest: exclude the argmin position only
    float v2 = (kk == mi) ? 3.0e38f : v;
#pragma unroll
    for (int s = 16; s >= 1; s >>= 1)
        v2 = fminf(v2, __shfl_xor(v2, s, 64));

    // one-hot c, coalesced (64 consecutive floats per wave)
    c_out[pair * 32 + kk] = (kk == mi) ? 1.0f : 0.0f;

    if (kk == 0) {
        top1_ws[pair]   = mv;
        delta_ws[pair]  = v2 - mv;
        argmin_ws[pair] = mi;
    }
}

// ---------------------------------------------------------------------------
// K3: single block. LDS bincount of argmins -> batch_c_mean / batch_value,
// per-r obj sums, EMA updates, obj_mean.
// ---------------------------------------------------------------------------
__global__ __launch_bounds__(256) void k3_final(
    const float* __restrict__ top1_ws, const float* __restrict__ delta_ws,
    const int* __restrict__ argmin_ws,
    const float* __restrict__ c_mean, const float* __restrict__ value,
    float* __restrict__ obj_out, float* __restrict__ obj_mean_out,
    float* __restrict__ ncm_out, float* __restrict__ nv_out)
{
    __shared__ float s_cnt[R_ * K_];
    __shared__ float s_val[R_ * K_];
    __shared__ float s_obj[R_];

    const int t = threadIdx.x;          // t = r*32 + k
    s_cnt[t] = 0.f;
    s_val[t] = 0.f;
    if (t < R_) s_obj[t] = 0.f;
    __syncthreads();

    for (int p = t; p < B_ * R_; p += 256) {
        const int r = p & (R_ - 1);
        const int a = argmin_ws[p];
        atomicAdd(&s_cnt[r * K_ + a], 1.0f);
        atomicAdd(&s_val[r * K_ + a], delta_ws[p]);
        atomicAdd(&s_obj[r], top1_ws[p]);
    }
    __syncthreads();

    ncm_out[t] = 0.9f * c_mean[t] + 0.1f * (s_cnt[t] * (1.0f / B_));
    nv_out[t]  = 0.9f * value[t]  + 0.1f * (s_val[t] * (1.0f / B_));
    if (t < R_) obj_out[t] = s_obj[t] * (1.0f / B_);
    if (t == 0) {
        float m = 0.f;
        for (int i = 0; i < R_; ++i) m += s_obj[i];
        obj_mean_out[0] = m * (1.0f / (B_ * R_));
    }
}

// ---------------------------------------------------------------------------
extern "C" void kernel_launch(void* const* d_in, const int* in_sizes, int n_in,
                              void* d_out, int out_size, void* d_ws, size_t ws_size,
                              hipStream_t stream)
{
    const float* x      = (const float*)d_in[0];   // (B, D)
    const float* z      = (const float*)d_in[1];   // (R, K, B, L)
    const float* Us     = (const float*)d_in[2];   // (R, K, D, L)
    const float* c_mean = (const float*)d_in[3];   // (R, K)
    const float* value  = (const float*)d_in[4];   // (R, K)

    float* out          = (float*)d_out;
    float* x_out        = out;                                   // R*K*B*D = 67108864
    float* c_out        = x_out + (size_t)R_ * K_ * B_ * D_;     // B*R*K   =   262144
    float* obj_out      = c_out + (size_t)B_ * R_ * K_;          // R       =        8
    float* obj_mean_out = obj_out + R_;                          // 1
    float* ncm_out      = obj_mean_out + 1;                      // R*K     =      256
    float* nv_out       = ncm_out + R_ * K_;                     // R*K     =      256

    float* loss_ws   = (float*)d_ws;                             // B*R*K floats
    float* top1_ws   = loss_ws + (size_t)B_ * R_ * K_;           // B*R floats
    float* delta_ws  = top1_ws + B_ * R_;                        // B*R floats
    int*   argmin_ws = (int*)(delta_ws + B_ * R_);               // B*R ints

    // K1: 256 (r,k) pairs x 8 b-chunks
    k1_gemm_loss<<<R_ * K_ * (B_ / BCHUNK), 256, 0, stream>>>(
        x, z, Us, x_out, loss_ws);
    // K2: 8192 pairs x 32 lanes = 262144 threads
    k2_top2<<<(B_ * R_ * 32) / 256, 256, 0, stream>>>(
        loss_ws, c_out, top1_ws, delta_ws, argmin_ws);
    // K3: final reductions + EMA
    k3_final<<<1, 256, 0, stream>>>(
        top1_ws, delta_ws, argmin_ws, c_mean, value,
        obj_out, obj_mean_out, ncm_out, nv_out);
}

// Round 3
// 385.988 us; speedup vs baseline: 1.0090x; 1.0090x over previous
//
#include <hip/hip_runtime.h>

// Problem constants
#define R_ 8
#define K_ 32
#define B_ 1024
#define D_ 256
#define L_ 16
#define BCHUNK 128   // b-rows per block in K1

// g_accum layout (floats, in ws after loss_ws):
//   [0,256)   cnt[r*32+k]
//   [256,512) val[r*32+k]
//   [512,520) obj[r]
//   [520]     (int) arrival counter
#define GA_CNT 0
#define GA_VAL 256
#define GA_OBJ 512
#define GA_CTR 520

// native vector type for nontemporal stores (HIP float4 is a class and
// __builtin_nontemporal_store rejects it)
typedef float nfloat4 __attribute__((ext_vector_type(4)));

__device__ __forceinline__ float2 f2fma(float s, float2 u, float2 a) {
    a.x = fmaf(s, u.x, a.x);
    a.y = fmaf(s, u.y, a.y);
    return a;
}

// ---------------------------------------------------------------------------
// K1: fused x_ = z @ Us^T (per r,k) + loss[b,r,k] = 0.5*sum_D (x - x_)^2
// grid: R*K*8 = 2048 blocks, 256 threads. Each lane owns 4 consecutive D
// columns (Us rows in 64 VGPRs as float2 pairs -> v_pk_fma_f32). Each wave
// does 32 b-rows, 2 at a time (hoisted loads, 2 independent shfl chains).
// Block 0 additionally zero-inits the global accumulators for K2.
// ---------------------------------------------------------------------------
__global__ __launch_bounds__(256) void k1_gemm_loss(
    const float* __restrict__ x, const float* __restrict__ z,
    const float* __restrict__ Us, float* __restrict__ x_out,
    float* __restrict__ loss_ws, float* __restrict__ g_accum)
{
    if (blockIdx.x == 0) {
        const int t = threadIdx.x;
        g_accum[GA_CNT + t] = 0.f;
        g_accum[GA_VAL + t] = 0.f;
        if (t < R_) g_accum[GA_OBJ + t] = 0.f;
        if (t == 0) ((int*)g_accum)[GA_CTR] = 0;
    }

    const int blk   = blockIdx.x;
    const int rk    = blk >> 3;
    const int chunk = blk & 7;
    const int r = rk >> 5;
    const int k = rk & 31;
    const int lane = threadIdx.x & 63;
    const int wave = threadIdx.x >> 6;

    const float* Us_rk = Us + (size_t)rk * (D_ * L_);
    const float* z_rk  = z  + (size_t)rk * (B_ * L_);
    float*       xo_rk = x_out + (size_t)rk * (B_ * D_);

    // Pack Us rows for this lane's 4 D columns into float2 pairs:
    // u01[j] = (Us[d0][j], Us[d0+1][j]),  u23[j] = (Us[d0+2][j], Us[d0+3][j])
    const int d0 = lane << 2;
    float2 u01[16], u23[16];
    {
        const float4* r0 = (const float4*)(Us_rk + (size_t)(d0 + 0) * L_);
        const float4* r1 = (const float4*)(Us_rk + (size_t)(d0 + 1) * L_);
        const float4* r2 = (const float4*)(Us_rk + (size_t)(d0 + 2) * L_);
        const float4* r3 = (const float4*)(Us_rk + (size_t)(d0 + 3) * L_);
#pragma unroll
        for (int j4 = 0; j4 < 4; ++j4) {
            float4 a = r0[j4], b = r1[j4], c = r2[j4], d = r3[j4];
            u01[j4 * 4 + 0] = make_float2(a.x, b.x);
            u01[j4 * 4 + 1] = make_float2(a.y, b.y);
            u01[j4 * 4 + 2] = make_float2(a.z, b.z);
            u01[j4 * 4 + 3] = make_float2(a.w, b.w);
            u23[j4 * 4 + 0] = make_float2(c.x, d.x);
            u23[j4 * 4 + 1] = make_float2(c.y, d.y);
            u23[j4 * 4 + 2] = make_float2(c.z, d.z);
            u23[j4 * 4 + 3] = make_float2(c.w, d.w);
        }
    }

    const int b0 = chunk * BCHUNK + wave * (BCHUNK / 4);   // 32 rows per wave
    for (int i = 0; i < BCHUNK / 4; i += 2) {
        const int ba = b0 + i;
        const int bb = b0 + i + 1;

        // ---- hoist ALL loads for both rows (max MLP) ----
        const float4* zra = (const float4*)(z_rk + (size_t)ba * L_);
        const float4* zrb = (const float4*)(z_rk + (size_t)bb * L_);
        float4 zA[4], zB[4];
#pragma unroll
        for (int j4 = 0; j4 < 4; ++j4) { zA[j4] = zra[j4]; zB[j4] = zrb[j4]; }
        float4 xa = ((const float4*)(x + (size_t)ba * D_))[lane];
        float4 xb = ((const float4*)(x + (size_t)bb * D_))[lane];

        // ---- packed-fp32 dot products ----
        float2 a01 = make_float2(0.f, 0.f), a23 = make_float2(0.f, 0.f);
        float2 b01 = make_float2(0.f, 0.f), b23 = make_float2(0.f, 0.f);
#pragma unroll
        for (int j4 = 0; j4 < 4; ++j4) {
            float4 za = zA[j4], zb = zB[j4];
            a01 = f2fma(za.x, u01[4 * j4 + 0], a01); a23 = f2fma(za.x, u23[4 * j4 + 0], a23);
            a01 = f2fma(za.y, u01[4 * j4 + 1], a01); a23 = f2fma(za.y, u23[4 * j4 + 1], a23);
            a01 = f2fma(za.z, u01[4 * j4 + 2], a01); a23 = f2fma(za.z, u23[4 * j4 + 2], a23);
            a01 = f2fma(za.w, u01[4 * j4 + 3], a01); a23 = f2fma(za.w, u23[4 * j4 + 3], a23);
            b01 = f2fma(zb.x, u01[4 * j4 + 0], b01); b23 = f2fma(zb.x, u23[4 * j4 + 0], b23);
            b01 = f2fma(zb.y, u01[4 * j4 + 1], b01); b23 = f2fma(zb.y, u23[4 * j4 + 1], b23);
            b01 = f2fma(zb.z, u01[4 * j4 + 2], b01); b23 = f2fma(zb.z, u23[4 * j4 + 2], b23);
            b01 = f2fma(zb.w, u01[4 * j4 + 3], b01); b23 = f2fma(zb.w, u23[4 * j4 + 3], b23);
        }

        // ---- streaming nontemporal stores of x_ (never re-read) ----
        nfloat4 oA = { a01.x, a01.y, a23.x, a23.y };
        nfloat4 oB = { b01.x, b01.y, b23.x, b23.y };
        __builtin_nontemporal_store(oA, (nfloat4*)(xo_rk + (size_t)ba * D_) + lane);
        __builtin_nontemporal_store(oB, (nfloat4*)(xo_rk + (size_t)bb * D_) + lane);

        // ---- fused loss: two independent 6-step shfl chains ----
        float dax = xa.x - oA.x, day = xa.y - oA.y, daz = xa.z - oA.z, daw = xa.w - oA.w;
        float dbx = xb.x - oB.x, dby = xb.y - oB.y, dbz = xb.z - oB.z, dbw = xb.w - oB.w;
        float sqA = fmaf(dax, dax, fmaf(day, day, fmaf(daz, daz, daw * daw)));
        float sqB = fmaf(dbx, dbx, fmaf(dby, dby, fmaf(dbz, dbz, dbw * dbw)));
#pragma unroll
        for (int s = 32; s >= 1; s >>= 1) {
            sqA += __shfl_xor(sqA, s, 64);
            sqB += __shfl_xor(sqB, s, 64);
        }
        if (lane == 0) {
            loss_ws[((size_t)ba * R_ + r) * K_ + k] = 0.5f * sqA;
            loss_ws[((size_t)bb * R_ + r) * K_ + k] = 0.5f * sqB;
        }
    }
}

// ---------------------------------------------------------------------------
// K2 (fused with old K3): grid = 32 blocks x 256 threads. Each block handles
// 256 (b,r) pairs (8 concurrent pairs x 32 iterations). Pair-leader thread
// (kk==0) has sub == pair%8 == r, so it exclusively owns LDS histogram row r
// -> plain LDS read-modify-write, no atomics. Block partials -> global float
// atomics; arrival counter; last block computes EMA/obj epilogue.
// ---------------------------------------------------------------------------
__global__ __launch_bounds__(256) void k2_top2_final(
    const float* __restrict__ loss_ws, const float* __restrict__ c_mean,
    const float* __restrict__ value, float* __restrict__ c_out,
    float* __restrict__ obj_out, float* __restrict__ obj_mean_out,
    float* __restrict__ ncm_out, float* __restrict__ nv_out,
    float* __restrict__ g_accum, int nblocks)
{
    __shared__ float s_cnt[R_ * K_];
    __shared__ float s_val[R_ * K_];
    __shared__ float s_obj[R_];
    __shared__ int   s_last;

    const int t   = threadIdx.x;
    const int kk  = t & 31;
    const int sub = t >> 5;          // 0..7; for leaders, sub == r of the pair
    s_cnt[t] = 0.f;
    s_val[t] = 0.f;
    __syncthreads();

    float obj_local = 0.f;

    for (int it = 0; it < 32; ++it) {
        const int pair = blockIdx.x * 256 + it * 8 + sub;   // pair = b*R + r
        const float v = loss_ws[pair * 32 + kk];

        // min + argmin within 32 lanes (xor masks <=16 keep halves separate);
        // lowest index wins ties, matching jax.lax.top_k
        float mv = v; int mi = kk;
#pragma unroll
        for (int s = 16; s >= 1; s >>= 1) {
            float ov = __shfl_xor(mv, s, 64);
            int   oi = __shfl_xor(mi, s, 64);
            if (ov < mv || (ov == mv && oi < mi)) { mv = ov; mi = oi; }
        }
        // second-smallest: exclude only the argmin position
        float v2 = (kk == mi) ? 3.0e38f : v;
#pragma unroll
        for (int s = 16; s >= 1; s >>= 1)
            v2 = fminf(v2, __shfl_xor(v2, s, 64));

        // one-hot c, coalesced
        c_out[pair * 32 + kk] = (kk == mi) ? 1.0f : 0.0f;

        if (kk == 0) {   // leader exclusively owns LDS row `sub`
            s_cnt[sub * 32 + mi] += 1.0f;
            s_val[sub * 32 + mi] += v2 - mv;
            obj_local += mv;
        }
    }
    if (kk == 0) s_obj[sub] = obj_local;
    __syncthreads();

    // block partials -> global accumulators (device-scope atomics)
    atomicAdd(&g_accum[GA_CNT + t], s_cnt[t]);
    atomicAdd(&g_accum[GA_VAL + t], s_val[t]);
    if (t < R_) atomicAdd(&g_accum[GA_OBJ + t], s_obj[t]);
    __threadfence();

    if (t == 0) {
        int prev = atomicAdd((int*)g_accum + GA_CTR, 1);
        s_last = (prev == nblocks - 1) ? 1 : 0;
    }
    __syncthreads();

    if (s_last) {
        // coherent reads of completed accumulators via atomic RMW(+0)
        float cnt = atomicAdd(&g_accum[GA_CNT + t], 0.f);
        float val = atomicAdd(&g_accum[GA_VAL + t], 0.f);
        ncm_out[t] = 0.9f * c_mean[t] + 0.1f * (cnt * (1.0f / B_));
        nv_out[t]  = 0.9f * value[t]  + 0.1f * (val * (1.0f / B_));
        if (t < R_) {
            float o = atomicAdd(&g_accum[GA_OBJ + t], 0.f);
            obj_out[t] = o * (1.0f / B_);
        }
        if (t == 0) {
            float m = 0.f;
            for (int i = 0; i < R_; ++i) m += atomicAdd(&g_accum[GA_OBJ + i], 0.f);
            obj_mean_out[0] = m * (1.0f / (B_ * R_));
        }
    }
}

// ---------------------------------------------------------------------------
extern "C" void kernel_launch(void* const* d_in, const int* in_sizes, int n_in,
                              void* d_out, int out_size, void* d_ws, size_t ws_size,
                              hipStream_t stream)
{
    const float* x      = (const float*)d_in[0];   // (B, D)
    const float* z      = (const float*)d_in[1];   // (R, K, B, L)
    const float* Us     = (const float*)d_in[2];   // (R, K, D, L)
    const float* c_mean = (const float*)d_in[3];   // (R, K)
    const float* value  = (const float*)d_in[4];   // (R, K)

    float* out          = (float*)d_out;
    float* x_out        = out;                                   // R*K*B*D
    float* c_out        = x_out + (size_t)R_ * K_ * B_ * D_;     // B*R*K
    float* obj_out      = c_out + (size_t)B_ * R_ * K_;          // R
    float* obj_mean_out = obj_out + R_;                          // 1
    float* ncm_out      = obj_mean_out + 1;                      // R*K
    float* nv_out       = ncm_out + R_ * K_;                     // R*K

    float* loss_ws = (float*)d_ws;                               // B*R*K floats
    float* g_accum = loss_ws + (size_t)B_ * R_ * K_;             // 521 floats

    k1_gemm_loss<<<R_ * K_ * (B_ / BCHUNK), 256, 0, stream>>>(
        x, z, Us, x_out, loss_ws, g_accum);

    const int nblocks = 32;
    k2_top2_final<<<nblocks, 256, 0, stream>>>(
        loss_ws, c_mean, value, c_out,
        obj_out, obj_mean_out, ncm_out, nv_out, g_accum, nblocks);
}